// Round 7
// baseline (229.528 us; speedup 1.0000x reference)
//
#include <hip/hip_runtime.h>
#include <hip/hip_bf16.h>
#include <cstdint>
#include <cstddef>

#define S_LEN 2048
#define DMODEL 1024
#define NHEAD 16
#define HDK 64
#define LOG2E 1.44269504088896340736f

typedef __attribute__((ext_vector_type(8))) __bf16 bf16x8;
typedef __attribute__((ext_vector_type(4))) __bf16 bf16x4;
typedef __attribute__((ext_vector_type(4))) float f32x4;
typedef __attribute__((ext_vector_type(16))) float f32x16;
typedef __attribute__((ext_vector_type(4))) unsigned int u32x4;

#define MFMA16(a, b, c) __builtin_amdgcn_mfma_f32_16x16x32_bf16((a), (b), (c), 0, 0, 0)
#define MFMA32(a, b, c) __builtin_amdgcn_mfma_f32_32x32x16_bf16((a), (b), (c), 0, 0, 0)

// async global->LDS, 16B per lane; LDS dest = wave-uniform base + lane*16
#define GLL16(g, l)                                                        \
  __builtin_amdgcn_global_load_lds(                                        \
      (const __attribute__((address_space(1))) unsigned int*)(g),          \
      (__attribute__((address_space(3))) unsigned int*)(l), 16, 0, 0)

// Fragment-tiled layouts (per (b,h) plane of S_LEN x 64):
__device__ __forceinline__ size_t qk_off(int s, int d) {
  return ((((size_t)(s >> 5) * 4 + (d >> 4)) * 2 + ((d >> 3) & 1)) * 32 + (s & 31)) * 8 + (d & 7);
}
__device__ __forceinline__ size_t v_off(int s, int d) {
  return ((size_t)(s >> 4) * 64 + d) * 16 + (s & 15);
}

// pack two f32 -> one dword of 2 bf16 (lo = first)
__device__ __forceinline__ unsigned pk2(float a, float b) {
  union { __bf16 h[2]; unsigned u; } cv;
  cv.h[0] = (__bf16)a;
  cv.h[1] = (__bf16)b;
  return cv.u;
}

// ---------------- f32 -> bf16 convert ----------------
__global__ __launch_bounds__(256) void k_cvt(const float* __restrict__ src,
                                             __bf16* __restrict__ dst, int n4) {
  const int i = blockIdx.x * 256 + threadIdx.x;
  if (i >= n4) return;
  const float4 v = reinterpret_cast<const float4*>(src)[i];
  bf16x4 o = { (__bf16)v.x, (__bf16)v.y, (__bf16)v.z, (__bf16)v.w };
  reinterpret_cast<bf16x4*>(dst)[i] = o;
}

// ================= 128x128 m97-structure GEMM core (shared by qkv/oproj) =======
// C[m][e] = sum_d A[m][d] * B[e][d], both row-major K-contiguous (A*B^T form).
// LDS linear [128][64] bf16 per operand; global source column-slot XOR-swizzled
// by (row&7) so ds_read_b128 fragment reads (same XOR) are ~2-way conflict-free.
// Staging: 8x global_load_lds_dwordx4 per K-step; 2 barriers; 32 MFMA/wave/step.

#define GEMM128_CORE(Abase, Bbase)                                             \
  __shared__ __align__(16) __bf16 As[128 * 64];                                \
  __shared__ __align__(16) __bf16 Bs[128 * 64];                                \
  const int t = threadIdx.x;                                                   \
  const int lane = t & 63;                                                     \
  const int w = t >> 6;                                                        \
  const int wm = (w >> 1) * 64;                                                \
  const int wn = (w & 1) * 64;                                                 \
  const int l15 = lane & 15, lhi = lane >> 4;                                  \
  const int lr = lane >> 3;               /* staging row-in-group 0..7 */      \
  const int ls = (lane & 7) ^ lr;         /* swizzled source slot */           \
  const int srow = w * 32 + lr;           /* staging row (+c*8) */             \
  const __bf16* gA = (Abase) + (size_t)(m0 + srow) * DMODEL + ls * 8;          \
  const __bf16* gB = (Bbase) + (size_t)(n0 + srow) * DMODEL + ls * 8;          \
  const f32x4 z4 = {0.f, 0.f, 0.f, 0.f};                                       \
  f32x4 acc[4][4];                                                             \
  _Pragma("unroll") for (int i = 0; i < 4; ++i)                                \
      _Pragma("unroll") for (int j = 0; j < 4; ++j) acc[i][j] = z4;            \
  for (int k0 = 0; k0 < DMODEL; k0 += 64) {                                    \
    _Pragma("unroll") for (int c = 0; c < 4; ++c) {                            \
      GLL16(gA + k0 + (size_t)c * 8 * DMODEL, &As[w * 2048 + c * 512]);        \
      GLL16(gB + k0 + (size_t)c * 8 * DMODEL, &Bs[w * 2048 + c * 512]);        \
    }                                                                          \
    __syncthreads();                                                           \
    _Pragma("unroll") for (int kk = 0; kk < 2; ++kk) {                         \
      const int sw = ((kk * 4 + lhi) ^ (l15 & 7)) * 8;                         \
      bf16x8 af[4], bf[4];                                                     \
      _Pragma("unroll") for (int i = 0; i < 4; ++i) {                          \
        af[i] = *reinterpret_cast<const bf16x8*>(                              \
            &As[(wm + i * 16 + l15) * 64 + sw]);                               \
        bf[i] = *reinterpret_cast<const bf16x8*>(                              \
            &Bs[(wn + i * 16 + l15) * 64 + sw]);                               \
      }                                                                        \
      _Pragma("unroll") for (int i = 0; i < 4; ++i)                            \
          _Pragma("unroll") for (int j = 0; j < 4; ++j)                        \
              acc[i][j] = MFMA16(af[i], bf[j], acc[i][j]);                     \
    }                                                                          \
    __syncthreads();                                                           \
  }

// ---------------- fused QKV projection + RoPE (128x128) ----------------
// z=0: Q (rope, pre-scaled 1/8, QK-tiled)  z=1: K (rope, QK-tiled)  z=2: V (V-tiled)
__global__ __launch_bounds__(256) void k_qkv(
    const __bf16* __restrict__ Xb,
    const __bf16* __restrict__ Wqb, const __bf16* __restrict__ Wkb,
    const __bf16* __restrict__ Wvb, const int* __restrict__ tpos,
    __bf16* __restrict__ Qr, __bf16* __restrict__ Kr, __bf16* __restrict__ Vt) {
  const int z = blockIdx.z;
  const __bf16* W = (z == 0) ? Wqb : (z == 1) ? Wkb : Wvb;
  const int m0 = blockIdx.x * 128;
  const int n0 = blockIdx.y * 128;

  GEMM128_CORE(Xb, W)

#pragma unroll
  for (int mi = 0; mi < 4; ++mi) {
#pragma unroll
    for (int ni = 0; ni < 4; ++ni) {
      const int e = n0 + wn + ni * 16 + l15;
      const int h = e >> 6, dkI = e & 63;
      if (z < 2) {
        // RoPE: pair (2i, 2i+1), ang = pos * theta^(-2i/64)
        const float invf = exp2f(-(float)(dkI & ~1) * (13.287712379549449f / 64.0f));
        const float oscale = (z == 0) ? 0.125f : 1.0f;  // fold 1/sqrt(dk) into Q
        __bf16* Out = (z == 0) ? Qr : Kr;
#pragma unroll
        for (int r = 0; r < 4; ++r) {
          const int m = m0 + wm + mi * 16 + lhi * 4 + r;
          const int bb = m >> 11, ss = m & (S_LEN - 1);
          const float pos = (float)tpos[m];
          const float ang = pos * invf;
          const float cs = cosf(ang), sn = sinf(ang);
          const float own = acc[mi][ni][r];
          const float par = __shfl_xor(own, 1);
          const float val = (dkI & 1) ? (par * sn + own * cs) : (own * cs - par * sn);
          Out[(size_t)(bb * NHEAD + h) * (S_LEN * HDK) + qk_off(ss, dkI)] =
              (__bf16)(val * oscale);
        }
      } else {
#pragma unroll
        for (int r = 0; r < 4; ++r) {
          const int m = m0 + wm + mi * 16 + lhi * 4 + r;
          const int bb = m >> 11, ss = m & (S_LEN - 1);
          Vt[(size_t)(bb * NHEAD + h) * (S_LEN * HDK) + v_off(ss, dkI)] =
              (__bf16)acc[mi][ni][r];
        }
      }
    }
  }
}

// ---------------- output projection (128x128, f32 out) ----------------
__global__ __launch_bounds__(256) void k_oproj(
    const __bf16* __restrict__ Ob, const __bf16* __restrict__ Wob,
    float* __restrict__ out) {
  const int m0 = blockIdx.x * 128;
  const int n0 = blockIdx.y * 128;

  GEMM128_CORE(Ob, Wob)

#pragma unroll
  for (int mi = 0; mi < 4; ++mi) {
#pragma unroll
    for (int ni = 0; ni < 4; ++ni) {
      const int e = n0 + wn + ni * 16 + l15;
#pragma unroll
      for (int r = 0; r < 4; ++r) {
        const int m = m0 + wm + mi * 16 + lhi * 4 + r;
        out[(size_t)m * DMODEL + e] = acc[mi][ni][r];
      }
    }
  }
}

// ---------------- causal flash attention (QBLK=32, 32x32 MFMA, LDS-free) ----------------
// Verified Round-6 structure: fragment-tiled dense K/Q/V loads + K/V pipeline.
__global__ __launch_bounds__(256, 2) void k_attn(
    const __bf16* __restrict__ Qr, const __bf16* __restrict__ Kr,
    const __bf16* __restrict__ Vt, __bf16* __restrict__ Ob) {
  const int t = threadIdx.x, lane = t & 63, w = t >> 6;
  const int blk = blockIdx.x;
  const int qg = blk >> 5;               // 0..15, heavy-first
  const int bh = blk & 31;
  const int qtile = (15 - qg) * 4 + w;   // 0..63
  const int q0 = qtile * 32;
  const int l31 = lane & 31, hi = lane >> 5;

  const __bf16* Q = Qr + (size_t)bh * (S_LEN * HDK);
  const __bf16* K = Kr + (size_t)bh * (S_LEN * HDK);
  const __bf16* V = Vt + (size_t)bh * (S_LEN * HDK);

  // Q fragments: row q=l31, d = dc*16 + hi*8 + j  (tiled: dense, lane-stride 16B)
  bf16x8 qf[4];
#pragma unroll
  for (int dc = 0; dc < 4; ++dc)
    qf[dc] = *reinterpret_cast<const bf16x8*>(
        &Q[((((size_t)(q0 >> 5) * 4 + dc) * 2 + hi) * 32 + l31) * 8]);

  f32x16 accO[2] = {};
  float m_run = -3e30f, l_run = 0.0f;
  const int q = q0 + l31;
  const int kmax = q0 + 32;

  // preload K fragments for k0 = 0 (2 tiles of 32 rows x 4 d-chunks)
  bf16x8 kf[2][4];
#pragma unroll
  for (int tt = 0; tt < 2; ++tt)
#pragma unroll
    for (int dc = 0; dc < 4; ++dc)
      kf[tt][dc] = *reinterpret_cast<const bf16x8*>(
          &K[((((size_t)tt * 4 + dc) * 2 + hi) * 32 + l31) * 8]);

  for (int k0 = 0; k0 < kmax; k0 += 64) {
    // ---- prefetch V fragments for THIS iteration (window = QK + softmax) ----
    bf16x8 vf[4][2];
#pragma unroll
    for (int ttc = 0; ttc < 4; ++ttc) {
      const int kc = k0 + ttc * 16;
#pragma unroll
      for (int d0h = 0; d0h < 2; ++d0h)
        vf[ttc][d0h] = *reinterpret_cast<const bf16x8*>(
            &V[((size_t)(kc >> 4) * 64 + d0h * 32 + l31) * 16 + hi * 8]);
    }

    // ---- QK^T (swapped): two 32k x 32q tiles ----
    f32x16 sT0 = {}, sT1 = {};
#pragma unroll
    for (int dc = 0; dc < 4; ++dc) {
      sT0 = MFMA32(kf[0][dc], qf[dc], sT0);
      sT1 = MFMA32(kf[1][dc], qf[dc], sT1);
    }

    // ---- reload K fragments for NEXT iteration (window = softmax + PV) ----
    if (k0 + 64 < kmax) {
      const int kn = (k0 + 64) >> 5;
#pragma unroll
      for (int tt = 0; tt < 2; ++tt)
#pragma unroll
        for (int dc = 0; dc < 4; ++dc)
          kf[tt][dc] = *reinterpret_cast<const bf16x8*>(
              &K[((((size_t)(kn + tt) * 4 + dc) * 2 + hi) * 32 + l31) * 8]);
    }

    // ---- causal mask + in-register max ----
    const bool maskIt = (k0 + 63 > q0);
    float mx = -3e30f;
#pragma unroll
    for (int r = 0; r < 16; ++r) {
      float s0 = sT0[r], s1 = sT1[r];
      if (maskIt) {
        const int kb = (r & 3) + ((r >> 2) << 3) + hi * 4;
        if (k0 + kb > q) s0 = -3e30f;
        if (k0 + 32 + kb > q) s1 = -3e30f;
      }
      sT0[r] = s0;
      sT1[r] = s1;
      mx = fmaxf(mx, fmaxf(s0, s1));
    }
    mx = fmaxf(mx, __shfl_xor(mx, 32));

    // ---- defer-max: rescale only when max grew past threshold ----
    float sc = 1.0f;
    if (!__all(mx <= m_run + 8.0f)) {
      const float mn = fmaxf(m_run, mx);
      sc = exp2f((m_run - mn) * LOG2E);
      m_run = mn;
      float scA[16];
#pragma unroll
      for (int r = 0; r < 16; ++r)
        scA[r] = __shfl(sc, (r & 3) + ((r >> 2) << 3) + hi * 4);
#pragma unroll
      for (int dt = 0; dt < 2; ++dt)
#pragma unroll
        for (int r = 0; r < 16; ++r) accO[dt][r] *= scA[r];
    }

    // ---- exp + running sum + pack to bf16 dwords ----
    float rs = 0.0f;
    unsigned pd[16];
#pragma unroll
    for (int j = 0; j < 8; ++j) {
      const float p0 = exp2f((sT0[2 * j] - m_run) * LOG2E);
      const float p1 = exp2f((sT0[2 * j + 1] - m_run) * LOG2E);
      const float p2 = exp2f((sT1[2 * j] - m_run) * LOG2E);
      const float p3 = exp2f((sT1[2 * j + 1] - m_run) * LOG2E);
      rs += (p0 + p1) + (p2 + p3);
      pd[j] = pk2(p0, p1);
      pd[8 + j] = pk2(p2, p3);
    }
    rs += __shfl_xor(rs, 32);
    l_run = l_run * sc + rs;

    // ---- PV: build A-frags via cross-half shfl + select, accumulate ----
#pragma unroll
    for (int tt = 0; tt < 2; ++tt) {
#pragma unroll
      for (int c = 0; c < 2; ++c) {
        const int base = tt * 8 + c * 4;
        const unsigned a0 = pd[base + 0], a1 = pd[base + 1];
        const unsigned a2 = pd[base + 2], a3 = pd[base + 3];
        const unsigned x0 = __shfl_xor(a0, 32), x1 = __shfl_xor(a1, 32);
        const unsigned x2 = __shfl_xor(a2, 32), x3 = __shfl_xor(a3, 32);
        const unsigned w0 = hi ? x2 : a0;
        const unsigned w1 = hi ? x3 : a1;
        const unsigned w2 = hi ? a2 : x0;
        const unsigned w3 = hi ? a3 : x1;
        union { u32x4 u; bf16x8 v; } cv;
        cv.u = (u32x4){w0, w1, w2, w3};
        const bf16x8 pa = cv.v;
        const int ttc = tt * 2 + c;
        accO[0] = MFMA32(pa, vf[ttc][0], accO[0]);
        accO[1] = MFMA32(pa, vf[ttc][1], accO[1]);
      }
    }
  }

  // ---- epilogue: normalize and store ----
  const float inv = 1.0f / l_run;   // per q = l31
  const int b = bh >> 4, h = bh & 15;
#pragma unroll
  for (int r = 0; r < 16; ++r) {
    const int qrow = (r & 3) + ((r >> 2) << 3) + hi * 4;
    const float invr = __shfl(inv, qrow);
    const int qo = q0 + qrow;
    __bf16* Op = &Ob[((size_t)(b * S_LEN + qo)) * DMODEL + h * HDK + l31];
    Op[0] = (__bf16)(accO[0][r] * invr);
    Op[32] = (__bf16)(accO[1][r] * invr);
  }
}

extern "C" void kernel_launch(void* const* d_in, const int* in_sizes, int n_in,
                              void* d_out, int out_size, void* d_ws, size_t ws_size,
                              hipStream_t stream) {
  const float* x = (const float*)d_in[0];
  const int* tpos = (const int*)d_in[1];
  const float* Wq = (const float*)d_in[2];
  const float* Wk = (const float*)d_in[3];
  const float* Wv = (const float*)d_in[4];
  const float* Wo = (const float*)d_in[5];
  float* out = (float*)d_out;

  __bf16* ws = (__bf16*)d_ws;
  __bf16* Xb = ws;                    // 4096x1024
  __bf16* Wqb = Xb + 4194304;         // 1024x1024
  __bf16* Wkb = Wqb + 1048576;
  __bf16* Wvb = Wkb + 1048576;
  __bf16* Wob = Wvb + 1048576;
  __bf16* Qr = Wob + 1048576;         // [2][16] QK-tiled planes
  __bf16* Kr = Qr + 4194304;
  __bf16* Vt = Kr + 4194304;          // [2][16] V-tiled planes
  __bf16* Ob = Vt + 4194304;          // 4096x1024

  k_cvt<<<4096, 256, 0, stream>>>(x, Xb, 1048576);
  k_cvt<<<1024, 256, 0, stream>>>(Wq, Wqb, 262144);
  k_cvt<<<1024, 256, 0, stream>>>(Wk, Wkb, 262144);
  k_cvt<<<1024, 256, 0, stream>>>(Wv, Wvb, 262144);
  k_cvt<<<1024, 256, 0, stream>>>(Wo, Wob, 262144);

  dim3 g1(32, 8, 3);
  k_qkv<<<g1, 256, 0, stream>>>(Xb, Wqb, Wkb, Wvb, tpos, Qr, Kr, Vt);

  k_attn<<<512, 256, 0, stream>>>(Qr, Kr, Vt, Ob);

  dim3 g2(32, 8);
  k_oproj<<<g2, 256, 0, stream>>>(Ob, Wob, out);
}

// Round 8
// 135.303 us; speedup vs baseline: 1.6964x; 1.6964x over previous
//
#include <hip/hip_runtime.h>
#include <hip/hip_bf16.h>
#include <cstdint>
#include <cstddef>

#define S_LEN 2048
#define DMODEL 1024
#define NHEAD 16
#define HDK 64
#define LOG2E 1.44269504088896340736f

typedef __attribute__((ext_vector_type(8))) __bf16 bf16x8;
typedef __attribute__((ext_vector_type(4))) __bf16 bf16x4;
typedef __attribute__((ext_vector_type(4))) float f32x4;
typedef __attribute__((ext_vector_type(16))) float f32x16;
typedef __attribute__((ext_vector_type(4))) unsigned int u32x4;

#define MFMA16(a, b, c) __builtin_amdgcn_mfma_f32_16x16x32_bf16((a), (b), (c), 0, 0, 0)
#define MFMA32(a, b, c) __builtin_amdgcn_mfma_f32_32x32x16_bf16((a), (b), (c), 0, 0, 0)

// async global->LDS, 16B per lane; LDS dest = wave-uniform base + lane*16
#define GLL16(g, l)                                                        \
  __builtin_amdgcn_global_load_lds(                                        \
      (const __attribute__((address_space(1))) unsigned int*)(g),          \
      (__attribute__((address_space(3))) unsigned int*)(l), 16, 0, 0)

// Fragment-tiled layouts (per (b,h) plane of S_LEN x 64):
__device__ __forceinline__ size_t qk_off(int s, int d) {
  return ((((size_t)(s >> 5) * 4 + (d >> 4)) * 2 + ((d >> 3) & 1)) * 32 + (s & 31)) * 8 + (d & 7);
}
__device__ __forceinline__ size_t v_off(int s, int d) {
  return ((size_t)(s >> 4) * 64 + d) * 16 + (s & 15);
}

// pack two f32 -> one dword of 2 bf16 (lo = first)
__device__ __forceinline__ unsigned pk2(float a, float b) {
  union { __bf16 h[2]; unsigned u; } cv;
  cv.h[0] = (__bf16)a;
  cv.h[1] = (__bf16)b;
  return cv.u;
}

// ---------------- f32 -> bf16 convert ----------------
__global__ __launch_bounds__(256) void k_cvt(const float* __restrict__ src,
                                             __bf16* __restrict__ dst, int n4) {
  const int i = blockIdx.x * 256 + threadIdx.x;
  if (i >= n4) return;
  const float4 v = reinterpret_cast<const float4*>(src)[i];
  bf16x4 o = { (__bf16)v.x, (__bf16)v.y, (__bf16)v.z, (__bf16)v.w };
  reinterpret_cast<bf16x4*>(dst)[i] = o;
}

// ---------------- RoPE cos/sin table: tab[m][i] = (cos, sin)(pos[m]*theta^(-i/32)) ----
__global__ __launch_bounds__(256) void k_rope(const int* __restrict__ tpos,
                                              float2* __restrict__ tab) {
  const int idx = blockIdx.x * 256 + threadIdx.x;   // [0, 4096*32)
  const int m = idx >> 5, i = idx & 31;
  const float invf = exp2f(-(float)i * (13.287712379549449f / 32.0f));
  const float ang = (float)tpos[m] * invf;
  tab[idx] = make_float2(cosf(ang), sinf(ang));
}

// ================= 128x128 m97-structure GEMM core (shared by qkv/oproj) =======
// C[m][e] = sum_d A[m][d] * B[e][d], both row-major K-contiguous (A*B^T form).
// LDS linear [128][64] bf16 per operand; global source column-slot XOR-swizzled
// by (row&7) so ds_read_b128 fragment reads (same XOR) are ~2-way conflict-free.
// Staging: 8x global_load_lds_dwordx4 per K-step; 2 barriers; 32 MFMA/wave/step.

#define GEMM128_CORE(Abase, Bbase)                                             \
  __shared__ __align__(16) __bf16 As[128 * 64];                                \
  __shared__ __align__(16) __bf16 Bs[128 * 64];                                \
  const int t = threadIdx.x;                                                   \
  const int lane = t & 63;                                                     \
  const int w = t >> 6;                                                        \
  const int wm = (w >> 1) * 64;                                                \
  const int wn = (w & 1) * 64;                                                 \
  const int l15 = lane & 15, lhi = lane >> 4;                                  \
  const int lr = lane >> 3;               /* staging row-in-group 0..7 */      \
  const int ls = (lane & 7) ^ lr;         /* swizzled source slot */           \
  const int srow = w * 32 + lr;           /* staging row (+c*8) */             \
  const __bf16* gA = (Abase) + (size_t)(m0 + srow) * DMODEL + ls * 8;          \
  const __bf16* gB = (Bbase) + (size_t)(n0 + srow) * DMODEL + ls * 8;          \
  const f32x4 z4 = {0.f, 0.f, 0.f, 0.f};                                       \
  f32x4 acc[4][4];                                                             \
  _Pragma("unroll") for (int i = 0; i < 4; ++i)                                \
      _Pragma("unroll") for (int j = 0; j < 4; ++j) acc[i][j] = z4;            \
  for (int k0 = 0; k0 < DMODEL; k0 += 64) {                                    \
    _Pragma("unroll") for (int c = 0; c < 4; ++c) {                            \
      GLL16(gA + k0 + (size_t)c * 8 * DMODEL, &As[w * 2048 + c * 512]);        \
      GLL16(gB + k0 + (size_t)c * 8 * DMODEL, &Bs[w * 2048 + c * 512]);        \
    }                                                                          \
    __syncthreads();                                                           \
    _Pragma("unroll") for (int kk = 0; kk < 2; ++kk) {                         \
      const int sw = ((kk * 4 + lhi) ^ (l15 & 7)) * 8;                         \
      bf16x8 af[4], bf[4];                                                     \
      _Pragma("unroll") for (int i = 0; i < 4; ++i) {                          \
        af[i] = *reinterpret_cast<const bf16x8*>(                              \
            &As[(wm + i * 16 + l15) * 64 + sw]);                               \
        bf[i] = *reinterpret_cast<const bf16x8*>(                              \
            &Bs[(wn + i * 16 + l15) * 64 + sw]);                               \
      }                                                                        \
      _Pragma("unroll") for (int i = 0; i < 4; ++i)                            \
          _Pragma("unroll") for (int j = 0; j < 4; ++j)                        \
              acc[i][j] = MFMA16(af[i], bf[j], acc[i][j]);                     \
    }                                                                          \
    __syncthreads();                                                           \
  }

// ---------------- fused QKV projection + RoPE (128x128, table-based) ----------------
// z=0: Q (rope, pre-scaled 1/8, QK-tiled)  z=1: K (rope, QK-tiled)  z=2: V (V-tiled)
__global__ __launch_bounds__(256) void k_qkv(
    const __bf16* __restrict__ Xb,
    const __bf16* __restrict__ Wqb, const __bf16* __restrict__ Wkb,
    const __bf16* __restrict__ Wvb, const float2* __restrict__ rtab,
    __bf16* __restrict__ Qr, __bf16* __restrict__ Kr, __bf16* __restrict__ Vt) {
  const int z = blockIdx.z;
  const __bf16* W = (z == 0) ? Wqb : (z == 1) ? Wkb : Wvb;
  const int m0 = blockIdx.x * 128;
  const int n0 = blockIdx.y * 128;

  GEMM128_CORE(Xb, W)

  if (z < 2) {
    __bf16* Out = (z == 0) ? Qr : Kr;
    const float oscale = (z == 0) ? 0.125f : 1.0f;  // fold 1/sqrt(dk) into Q
#pragma unroll
    for (int mi = 0; mi < 4; ++mi) {
#pragma unroll
      for (int ni = 0; ni < 4; ++ni) {
        const int e = n0 + wn + ni * 16 + l15;
        const int h = e >> 6, dkI = e & 63;
#pragma unroll
        for (int r = 0; r < 4; ++r) {
          const int m = m0 + wm + mi * 16 + lhi * 4 + r;
          const int bb = m >> 11, ss = m & (S_LEN - 1);
          const float2 cssn = rtab[(size_t)m * 32 + (dkI >> 1)];
          const float own = acc[mi][ni][r];
          const float par = __shfl_xor(own, 1);
          const float val = (dkI & 1) ? (par * cssn.y + own * cssn.x)
                                      : (own * cssn.x - par * cssn.y);
          Out[(size_t)(bb * NHEAD + h) * (S_LEN * HDK) + qk_off(ss, dkI)] =
              (__bf16)(val * oscale);
        }
      }
    }
  } else {
#pragma unroll
    for (int mi = 0; mi < 4; ++mi) {
#pragma unroll
      for (int ni = 0; ni < 4; ++ni) {
        const int e = n0 + wn + ni * 16 + l15;
        const int h = e >> 6, dkI = e & 63;
#pragma unroll
        for (int r = 0; r < 4; ++r) {
          const int m = m0 + wm + mi * 16 + lhi * 4 + r;
          const int bb = m >> 11, ss = m & (S_LEN - 1);
          Vt[(size_t)(bb * NHEAD + h) * (S_LEN * HDK) + v_off(ss, dkI)] =
              (__bf16)acc[mi][ni][r];
        }
      }
    }
  }
}

// ---------------- output projection (128x128, f32 out) ----------------
__global__ __launch_bounds__(256) void k_oproj(
    const __bf16* __restrict__ Ob, const __bf16* __restrict__ Wob,
    float* __restrict__ out) {
  const int m0 = blockIdx.x * 128;
  const int n0 = blockIdx.y * 128;

  GEMM128_CORE(Ob, Wob)

#pragma unroll
  for (int mi = 0; mi < 4; ++mi) {
#pragma unroll
    for (int ni = 0; ni < 4; ++ni) {
      const int e = n0 + wn + ni * 16 + l15;
#pragma unroll
      for (int r = 0; r < 4; ++r) {
        const int m = m0 + wm + mi * 16 + lhi * 4 + r;
        out[(size_t)m * DMODEL + e] = acc[mi][ni][r];
      }
    }
  }
}

// ---------------- causal flash attention (QBLK=32, 32x32 MFMA, LDS-free) ----------------
// Verified Round-6 structure: fragment-tiled dense K/Q/V loads + K/V pipeline.
__global__ __launch_bounds__(256, 2) void k_attn(
    const __bf16* __restrict__ Qr, const __bf16* __restrict__ Kr,
    const __bf16* __restrict__ Vt, __bf16* __restrict__ Ob) {
  const int t = threadIdx.x, lane = t & 63, w = t >> 6;
  const int blk = blockIdx.x;
  const int qg = blk >> 5;               // 0..15, heavy-first
  const int bh = blk & 31;
  const int qtile = (15 - qg) * 4 + w;   // 0..63
  const int q0 = qtile * 32;
  const int l31 = lane & 31, hi = lane >> 5;

  const __bf16* Q = Qr + (size_t)bh * (S_LEN * HDK);
  const __bf16* K = Kr + (size_t)bh * (S_LEN * HDK);
  const __bf16* V = Vt + (size_t)bh * (S_LEN * HDK);

  // Q fragments: row q=l31, d = dc*16 + hi*8 + j  (tiled: dense, lane-stride 16B)
  bf16x8 qf[4];
#pragma unroll
  for (int dc = 0; dc < 4; ++dc)
    qf[dc] = *reinterpret_cast<const bf16x8*>(
        &Q[((((size_t)(q0 >> 5) * 4 + dc) * 2 + hi) * 32 + l31) * 8]);

  f32x16 accO[2] = {};
  float m_run = -3e30f, l_run = 0.0f;
  const int q = q0 + l31;
  const int kmax = q0 + 32;

  // preload K fragments for k0 = 0 (2 tiles of 32 rows x 4 d-chunks)
  bf16x8 kf[2][4];
#pragma unroll
  for (int tt = 0; tt < 2; ++tt)
#pragma unroll
    for (int dc = 0; dc < 4; ++dc)
      kf[tt][dc] = *reinterpret_cast<const bf16x8*>(
          &K[((((size_t)tt * 4 + dc) * 2 + hi) * 32 + l31) * 8]);

  for (int k0 = 0; k0 < kmax; k0 += 64) {
    // ---- prefetch V fragments for THIS iteration (window = QK + softmax) ----
    bf16x8 vf[4][2];
#pragma unroll
    for (int ttc = 0; ttc < 4; ++ttc) {
      const int kc = k0 + ttc * 16;
#pragma unroll
      for (int d0h = 0; d0h < 2; ++d0h)
        vf[ttc][d0h] = *reinterpret_cast<const bf16x8*>(
            &V[((size_t)(kc >> 4) * 64 + d0h * 32 + l31) * 16 + hi * 8]);
    }

    // ---- QK^T (swapped): two 32k x 32q tiles ----
    f32x16 sT0 = {}, sT1 = {};
#pragma unroll
    for (int dc = 0; dc < 4; ++dc) {
      sT0 = MFMA32(kf[0][dc], qf[dc], sT0);
      sT1 = MFMA32(kf[1][dc], qf[dc], sT1);
    }

    // ---- reload K fragments for NEXT iteration (window = softmax + PV) ----
    if (k0 + 64 < kmax) {
      const int kn = (k0 + 64) >> 5;
#pragma unroll
      for (int tt = 0; tt < 2; ++tt)
#pragma unroll
        for (int dc = 0; dc < 4; ++dc)
          kf[tt][dc] = *reinterpret_cast<const bf16x8*>(
              &K[((((size_t)(kn + tt) * 4 + dc) * 2 + hi) * 32 + l31) * 8]);
    }

    // ---- causal mask + in-register max ----
    const bool maskIt = (k0 + 63 > q0);
    float mx = -3e30f;
#pragma unroll
    for (int r = 0; r < 16; ++r) {
      float s0 = sT0[r], s1 = sT1[r];
      if (maskIt) {
        const int kb = (r & 3) + ((r >> 2) << 3) + hi * 4;
        if (k0 + kb > q) s0 = -3e30f;
        if (k0 + 32 + kb > q) s1 = -3e30f;
      }
      sT0[r] = s0;
      sT1[r] = s1;
      mx = fmaxf(mx, fmaxf(s0, s1));
    }
    mx = fmaxf(mx, __shfl_xor(mx, 32));

    // ---- defer-max: rescale only when max grew past threshold ----
    float sc = 1.0f;
    if (!__all(mx <= m_run + 8.0f)) {
      const float mn = fmaxf(m_run, mx);
      sc = exp2f((m_run - mn) * LOG2E);
      m_run = mn;
      float scA[16];
#pragma unroll
      for (int r = 0; r < 16; ++r)
        scA[r] = __shfl(sc, (r & 3) + ((r >> 2) << 3) + hi * 4);
#pragma unroll
      for (int dt = 0; dt < 2; ++dt)
#pragma unroll
        for (int r = 0; r < 16; ++r) accO[dt][r] *= scA[r];
    }

    // ---- exp + running sum + pack to bf16 dwords ----
    float rs = 0.0f;
    unsigned pd[16];
#pragma unroll
    for (int j = 0; j < 8; ++j) {
      const float p0 = exp2f((sT0[2 * j] - m_run) * LOG2E);
      const float p1 = exp2f((sT0[2 * j + 1] - m_run) * LOG2E);
      const float p2 = exp2f((sT1[2 * j] - m_run) * LOG2E);
      const float p3 = exp2f((sT1[2 * j + 1] - m_run) * LOG2E);
      rs += (p0 + p1) + (p2 + p3);
      pd[j] = pk2(p0, p1);
      pd[8 + j] = pk2(p2, p3);
    }
    rs += __shfl_xor(rs, 32);
    l_run = l_run * sc + rs;

    // ---- PV: build A-frags via cross-half shfl + select, accumulate ----
#pragma unroll
    for (int tt = 0; tt < 2; ++tt) {
#pragma unroll
      for (int c = 0; c < 2; ++c) {
        const int base = tt * 8 + c * 4;
        const unsigned a0 = pd[base + 0], a1 = pd[base + 1];
        const unsigned a2 = pd[base + 2], a3 = pd[base + 3];
        const unsigned x0 = __shfl_xor(a0, 32), x1 = __shfl_xor(a1, 32);
        const unsigned x2 = __shfl_xor(a2, 32), x3 = __shfl_xor(a3, 32);
        const unsigned w0 = hi ? x2 : a0;
        const unsigned w1 = hi ? x3 : a1;
        const unsigned w2 = hi ? a2 : x0;
        const unsigned w3 = hi ? a3 : x1;
        union { u32x4 u; bf16x8 v; } cv;
        cv.u = (u32x4){w0, w1, w2, w3};
        const bf16x8 pa = cv.v;
        const int ttc = tt * 2 + c;
        accO[0] = MFMA32(pa, vf[ttc][0], accO[0]);
        accO[1] = MFMA32(pa, vf[ttc][1], accO[1]);
      }
    }
  }

  // ---- epilogue: normalize and store ----
  const float inv = 1.0f / l_run;   // per q = l31
  const int b = bh >> 4, h = bh & 15;
#pragma unroll
  for (int r = 0; r < 16; ++r) {
    const int qrow = (r & 3) + ((r >> 2) << 3) + hi * 4;
    const float invr = __shfl(inv, qrow);
    const int qo = q0 + qrow;
    __bf16* Op = &Ob[((size_t)(b * S_LEN + qo)) * DMODEL + h * HDK + l31];
    Op[0] = (__bf16)(accO[0][r] * invr);
    Op[32] = (__bf16)(accO[1][r] * invr);
  }
}

extern "C" void kernel_launch(void* const* d_in, const int* in_sizes, int n_in,
                              void* d_out, int out_size, void* d_ws, size_t ws_size,
                              hipStream_t stream) {
  const float* x = (const float*)d_in[0];
  const int* tpos = (const int*)d_in[1];
  const float* Wq = (const float*)d_in[2];
  const float* Wk = (const float*)d_in[3];
  const float* Wv = (const float*)d_in[4];
  const float* Wo = (const float*)d_in[5];
  float* out = (float*)d_out;

  __bf16* ws = (__bf16*)d_ws;
  __bf16* Xb = ws;                    // 4096x1024
  __bf16* Wqb = Xb + 4194304;         // 1024x1024
  __bf16* Wkb = Wqb + 1048576;
  __bf16* Wvb = Wkb + 1048576;
  __bf16* Wob = Wvb + 1048576;
  __bf16* Qr = Wob + 1048576;         // [2][16] QK-tiled planes
  __bf16* Kr = Qr + 4194304;
  __bf16* Vt = Kr + 4194304;          // [2][16] V-tiled planes
  __bf16* Ob = Vt + 4194304;          // 4096x1024
  float2* rtab = (float2*)(Ob + 4194304);  // [4096][32] cos/sin

  k_cvt<<<4096, 256, 0, stream>>>(x, Xb, 1048576);
  k_cvt<<<1024, 256, 0, stream>>>(Wq, Wqb, 262144);
  k_cvt<<<1024, 256, 0, stream>>>(Wk, Wkb, 262144);
  k_cvt<<<1024, 256, 0, stream>>>(Wv, Wvb, 262144);
  k_cvt<<<1024, 256, 0, stream>>>(Wo, Wob, 262144);
  k_rope<<<512, 256, 0, stream>>>(tpos, rtab);

  dim3 g1(32, 8, 3);
  k_qkv<<<g1, 256, 0, stream>>>(Xb, Wqb, Wkb, Wvb, rtab, Qr, Kr, Vt);

  k_attn<<<512, 256, 0, stream>>>(Qr, Kr, Vt, Ob);

  dim3 g2(32, 8);
  k_oproj<<<g2, 256, 0, stream>>>(Ob, Wob, out);
}

// Round 9
// 120.372 us; speedup vs baseline: 1.9068x; 1.1240x over previous
//
#include <hip/hip_runtime.h>
#include <hip/hip_bf16.h>
#include <cstdint>
#include <cstddef>

#define S_LEN 2048
#define DMODEL 1024
#define NHEAD 16
#define HDK 64
#define LOG2E 1.44269504088896340736f

typedef __attribute__((ext_vector_type(8))) __bf16 bf16x8;
typedef __attribute__((ext_vector_type(4))) __bf16 bf16x4;
typedef __attribute__((ext_vector_type(4))) float f32x4;
typedef __attribute__((ext_vector_type(16))) float f32x16;
typedef __attribute__((ext_vector_type(4))) unsigned int u32x4;

#define MFMA16(a, b, c) __builtin_amdgcn_mfma_f32_16x16x32_bf16((a), (b), (c), 0, 0, 0)
#define MFMA32(a, b, c) __builtin_amdgcn_mfma_f32_32x32x16_bf16((a), (b), (c), 0, 0, 0)

// async global->LDS, 16B per lane; LDS dest = wave-uniform base + lane*16
#define GLL16(g, l)                                                        \
  __builtin_amdgcn_global_load_lds(                                        \
      (const __attribute__((address_space(1))) unsigned int*)(g),          \
      (__attribute__((address_space(3))) unsigned int*)(l), 16, 0, 0)

// Fragment-tiled layouts (per (b,h) plane of S_LEN x 64):
__device__ __forceinline__ size_t qk_off(int s, int d) {
  return ((((size_t)(s >> 5) * 4 + (d >> 4)) * 2 + ((d >> 3) & 1)) * 32 + (s & 31)) * 8 + (d & 7);
}
__device__ __forceinline__ size_t v_off(int s, int d) {
  return ((size_t)(s >> 4) * 64 + d) * 16 + (s & 15);
}

// pack two f32 -> one dword of 2 bf16 (lo = first)
__device__ __forceinline__ unsigned pk2(float a, float b) {
  union { __bf16 h[2]; unsigned u; } cv;
  cv.h[0] = (__bf16)a;
  cv.h[1] = (__bf16)b;
  return cv.u;
}

// ---------------- f32 -> bf16 convert ----------------
__global__ __launch_bounds__(256) void k_cvt(const float* __restrict__ src,
                                             __bf16* __restrict__ dst, int n4) {
  const int i = blockIdx.x * 256 + threadIdx.x;
  if (i >= n4) return;
  const float4 v = reinterpret_cast<const float4*>(src)[i];
  bf16x4 o = { (__bf16)v.x, (__bf16)v.y, (__bf16)v.z, (__bf16)v.w };
  reinterpret_cast<bf16x4*>(dst)[i] = o;
}

// ---------------- RoPE cos/sin table: tab[m][i] = (cos, sin)(pos[m]*theta^(-i/32)) ----
__global__ __launch_bounds__(256) void k_rope(const int* __restrict__ tpos,
                                              float2* __restrict__ tab) {
  const int idx = blockIdx.x * 256 + threadIdx.x;   // [0, 4096*32)
  const int m = idx >> 5, i = idx & 31;
  const float invf = exp2f(-(float)i * (13.287712379549449f / 32.0f));
  const float ang = (float)tpos[m] * invf;
  tab[idx] = make_float2(cosf(ang), sinf(ang));
}

// ================= 128x128 m97-structure GEMM core (shared by qkv/oproj) =======
#define GEMM128_CORE(Abase, Bbase)                                             \
  __shared__ __align__(16) __bf16 As[128 * 64];                                \
  __shared__ __align__(16) __bf16 Bs[128 * 64];                                \
  const int t = threadIdx.x;                                                   \
  const int lane = t & 63;                                                     \
  const int w = t >> 6;                                                        \
  const int wm = (w >> 1) * 64;                                                \
  const int wn = (w & 1) * 64;                                                 \
  const int l15 = lane & 15, lhi = lane >> 4;                                  \
  const int lr = lane >> 3;               /* staging row-in-group 0..7 */      \
  const int ls = (lane & 7) ^ lr;         /* swizzled source slot */           \
  const int srow = w * 32 + lr;           /* staging row (+c*8) */             \
  const __bf16* gA = (Abase) + (size_t)(m0 + srow) * DMODEL + ls * 8;          \
  const __bf16* gB = (Bbase) + (size_t)(n0 + srow) * DMODEL + ls * 8;          \
  const f32x4 z4 = {0.f, 0.f, 0.f, 0.f};                                       \
  f32x4 acc[4][4];                                                             \
  _Pragma("unroll") for (int i = 0; i < 4; ++i)                                \
      _Pragma("unroll") for (int j = 0; j < 4; ++j) acc[i][j] = z4;            \
  for (int k0 = 0; k0 < DMODEL; k0 += 64) {                                    \
    _Pragma("unroll") for (int c = 0; c < 4; ++c) {                            \
      GLL16(gA + k0 + (size_t)c * 8 * DMODEL, &As[w * 2048 + c * 512]);        \
      GLL16(gB + k0 + (size_t)c * 8 * DMODEL, &Bs[w * 2048 + c * 512]);        \
    }                                                                          \
    __syncthreads();                                                           \
    _Pragma("unroll") for (int kk = 0; kk < 2; ++kk) {                         \
      const int sw = ((kk * 4 + lhi) ^ (l15 & 7)) * 8;                         \
      bf16x8 af[4], bf[4];                                                     \
      _Pragma("unroll") for (int i = 0; i < 4; ++i) {                          \
        af[i] = *reinterpret_cast<const bf16x8*>(                              \
            &As[(wm + i * 16 + l15) * 64 + sw]);                               \
        bf[i] = *reinterpret_cast<const bf16x8*>(                              \
            &Bs[(wn + i * 16 + l15) * 64 + sw]);                               \
      }                                                                        \
      _Pragma("unroll") for (int i = 0; i < 4; ++i)                            \
          _Pragma("unroll") for (int j = 0; j < 4; ++j)                        \
              acc[i][j] = MFMA16(af[i], bf[j], acc[i][j]);                     \
    }                                                                          \
    __syncthreads();                                                           \
  }

// ---------------- fused QKV projection + RoPE (128x128, table-based) ----------------
// z=0: Q (rope, pre-scaled 0.125*log2e -> log2-domain softmax)  z=1: K  z=2: V
__global__ __launch_bounds__(256) void k_qkv(
    const __bf16* __restrict__ Xb,
    const __bf16* __restrict__ Wqb, const __bf16* __restrict__ Wkb,
    const __bf16* __restrict__ Wvb, const float2* __restrict__ rtab,
    __bf16* __restrict__ Qr, __bf16* __restrict__ Kr, __bf16* __restrict__ Vt) {
  const int z = blockIdx.z;
  const __bf16* W = (z == 0) ? Wqb : (z == 1) ? Wkb : Wvb;
  const int m0 = blockIdx.x * 128;
  const int n0 = blockIdx.y * 128;

  GEMM128_CORE(Xb, W)

  if (z < 2) {
    __bf16* Out = (z == 0) ? Qr : Kr;
    const float oscale = (z == 0) ? 0.125f * LOG2E : 1.0f;
#pragma unroll
    for (int mi = 0; mi < 4; ++mi) {
#pragma unroll
      for (int ni = 0; ni < 4; ++ni) {
        const int e = n0 + wn + ni * 16 + l15;
        const int h = e >> 6, dkI = e & 63;
#pragma unroll
        for (int r = 0; r < 4; ++r) {
          const int m = m0 + wm + mi * 16 + lhi * 4 + r;
          const int bb = m >> 11, ss = m & (S_LEN - 1);
          const float2 cssn = rtab[(size_t)m * 32 + (dkI >> 1)];
          const float own = acc[mi][ni][r];
          const float par = __shfl_xor(own, 1);
          const float val = (dkI & 1) ? (par * cssn.y + own * cssn.x)
                                      : (own * cssn.x - par * cssn.y);
          Out[(size_t)(bb * NHEAD + h) * (S_LEN * HDK) + qk_off(ss, dkI)] =
              (__bf16)(val * oscale);
        }
      }
    }
  } else {
#pragma unroll
    for (int mi = 0; mi < 4; ++mi) {
#pragma unroll
      for (int ni = 0; ni < 4; ++ni) {
        const int e = n0 + wn + ni * 16 + l15;
        const int h = e >> 6, dkI = e & 63;
#pragma unroll
        for (int r = 0; r < 4; ++r) {
          const int m = m0 + wm + mi * 16 + lhi * 4 + r;
          const int bb = m >> 11, ss = m & (S_LEN - 1);
          Vt[(size_t)(bb * NHEAD + h) * (S_LEN * HDK) + v_off(ss, dkI)] =
              (__bf16)acc[mi][ni][r];
        }
      }
    }
  }
}

// ---------------- output projection (128x128, f32 out) ----------------
__global__ __launch_bounds__(256) void k_oproj(
    const __bf16* __restrict__ Ob, const __bf16* __restrict__ Wob,
    float* __restrict__ out) {
  const int m0 = blockIdx.x * 128;
  const int n0 = blockIdx.y * 128;

  GEMM128_CORE(Ob, Wob)

#pragma unroll
  for (int mi = 0; mi < 4; ++mi) {
#pragma unroll
    for (int ni = 0; ni < 4; ++ni) {
      const int e = n0 + wn + ni * 16 + l15;
#pragma unroll
      for (int r = 0; r < 4; ++r) {
        const int m = m0 + wm + mi * 16 + lhi * 4 + r;
        out[(size_t)m * DMODEL + e] = acc[mi][ni][r];
      }
    }
  }
}

// ---------------- causal flash attention (QBLK=32, 32x32 MFMA, KV-split x2) ----------
// 2 waves per q-tile partition the k-tiles (stride 128); flash-combine via LDS.
// Softmax in log2 domain (Q pre-scaled by 0.125*log2e): p = exp2(s - m).
__global__ __launch_bounds__(256, 2) void k_attn(
    const __bf16* __restrict__ Qr, const __bf16* __restrict__ Kr,
    const __bf16* __restrict__ Vt, __bf16* __restrict__ Ob) {
  const int t = threadIdx.x, lane = t & 63, w = t >> 6;
  const int blk = blockIdx.x;            // 1024 blocks
  const int qp = blk >> 5;               // 0..31 qtile-pair, heavy-first
  const int bh = blk & 31;
  const int slot = w >> 1;               // which qtile in block (0,1)
  const int half = w & 1;                // k-range half
  const int qtile = (31 - qp) * 2 + slot;  // 0..63
  const int q0 = qtile * 32;
  const int l31 = lane & 31, hi = lane >> 5;

  const __bf16* Q = Qr + (size_t)bh * (S_LEN * HDK);
  const __bf16* K = Kr + (size_t)bh * (S_LEN * HDK);
  const __bf16* V = Vt + (size_t)bh * (S_LEN * HDK);

  __shared__ float mlb[2][2][64];                    // half1 stats (m, l)
  __shared__ __align__(16) float olb[2][64][32];     // half1 accO

  // Q fragments: row q=l31, d = dc*16 + hi*8 + j  (tiled: dense, lane-stride 16B)
  bf16x8 qf[4];
#pragma unroll
  for (int dc = 0; dc < 4; ++dc)
    qf[dc] = *reinterpret_cast<const bf16x8*>(
        &Q[((((size_t)(q0 >> 5) * 4 + dc) * 2 + hi) * 32 + l31) * 8]);

  f32x16 accO[2] = {};
  float m_run = -3e30f, l_run = 0.0f;
  const int q = q0 + l31;
  const int kmax = q0 + 32;

  // preload K fragments for first k0 of this half (always in-bounds rows)
  const int kstart = 64 * half;
  bf16x8 kf[2][4];
#pragma unroll
  for (int tt = 0; tt < 2; ++tt)
#pragma unroll
    for (int dc = 0; dc < 4; ++dc)
      kf[tt][dc] = *reinterpret_cast<const bf16x8*>(
          &K[((((size_t)((kstart >> 5) + tt) * 4 + dc) * 2 + hi) * 32 + l31) * 8]);

  for (int k0 = kstart; k0 < kmax; k0 += 128) {
    // ---- prefetch V fragments for THIS iteration ----
    bf16x8 vf[4][2];
#pragma unroll
    for (int ttc = 0; ttc < 4; ++ttc) {
      const int kc = k0 + ttc * 16;
#pragma unroll
      for (int d0h = 0; d0h < 2; ++d0h)
        vf[ttc][d0h] = *reinterpret_cast<const bf16x8*>(
            &V[((size_t)(kc >> 4) * 64 + d0h * 32 + l31) * 16 + hi * 8]);
    }

    // ---- QK^T (swapped): two 32k x 32q tiles ----
    f32x16 sT0 = {}, sT1 = {};
#pragma unroll
    for (int dc = 0; dc < 4; ++dc) {
      sT0 = MFMA32(kf[0][dc], qf[dc], sT0);
      sT1 = MFMA32(kf[1][dc], qf[dc], sT1);
    }

    // ---- reload K fragments for NEXT iteration of this half ----
    if (k0 + 128 < kmax) {
      const int kn = (k0 + 128) >> 5;
#pragma unroll
      for (int tt = 0; tt < 2; ++tt)
#pragma unroll
        for (int dc = 0; dc < 4; ++dc)
          kf[tt][dc] = *reinterpret_cast<const bf16x8*>(
              &K[((((size_t)(kn + tt) * 4 + dc) * 2 + hi) * 32 + l31) * 8]);
    }

    // ---- causal mask ----
    const bool maskIt = (k0 + 63 > q0);
    if (maskIt) {
#pragma unroll
      for (int r = 0; r < 16; ++r) {
        const int kb = (r & 3) + ((r >> 2) << 3) + hi * 4;
        if (k0 + kb > q) sT0[r] = -3e30f;
        if (k0 + 32 + kb > q) sT1[r] = -3e30f;
      }
    }

    // ---- tree row-max (depth ~5, not a 31-chain) ----
    float pm[8];
#pragma unroll
    for (int j = 0; j < 8; ++j)
      pm[j] = fmaxf(fmaxf(sT0[2 * j], sT0[2 * j + 1]),
                    fmaxf(sT1[2 * j], sT1[2 * j + 1]));
    pm[0] = fmaxf(pm[0], pm[4]); pm[1] = fmaxf(pm[1], pm[5]);
    pm[2] = fmaxf(pm[2], pm[6]); pm[3] = fmaxf(pm[3], pm[7]);
    float mx = fmaxf(fmaxf(pm[0], pm[1]), fmaxf(pm[2], pm[3]));
    mx = fmaxf(mx, __shfl_xor(mx, 32));

    // ---- defer-max (log2 units): rescale only when max grew past threshold ----
    float sc = 1.0f;
    if (!__all(mx <= m_run + 8.0f)) {
      const float mn = fmaxf(m_run, mx);
      sc = exp2f(m_run - mn);
      m_run = mn;
      float scA[16];
#pragma unroll
      for (int r = 0; r < 16; ++r)
        scA[r] = __shfl(sc, (r & 3) + ((r >> 2) << 3) + hi * 4);
#pragma unroll
      for (int dt = 0; dt < 2; ++dt)
#pragma unroll
        for (int r = 0; r < 16; ++r) accO[dt][r] *= scA[r];
    }

    // ---- exp2 + tree running sum + pack to bf16 dwords ----
    float rsp[4] = {0.f, 0.f, 0.f, 0.f};
    unsigned pd[16];
#pragma unroll
    for (int j = 0; j < 8; ++j) {
      const float p0 = exp2f(sT0[2 * j] - m_run);
      const float p1 = exp2f(sT0[2 * j + 1] - m_run);
      const float p2 = exp2f(sT1[2 * j] - m_run);
      const float p3 = exp2f(sT1[2 * j + 1] - m_run);
      rsp[j & 3] += (p0 + p1) + (p2 + p3);
      pd[j] = pk2(p0, p1);
      pd[8 + j] = pk2(p2, p3);
    }
    float rs = (rsp[0] + rsp[1]) + (rsp[2] + rsp[3]);
    rs += __shfl_xor(rs, 32);
    l_run = l_run * sc + rs;

    // ---- PV: build A-frags via cross-half shfl + select, accumulate ----
#pragma unroll
    for (int tt = 0; tt < 2; ++tt) {
#pragma unroll
      for (int c = 0; c < 2; ++c) {
        const int base = tt * 8 + c * 4;
        const unsigned a0 = pd[base + 0], a1 = pd[base + 1];
        const unsigned a2 = pd[base + 2], a3 = pd[base + 3];
        const unsigned x0 = __shfl_xor(a0, 32), x1 = __shfl_xor(a1, 32);
        const unsigned x2 = __shfl_xor(a2, 32), x3 = __shfl_xor(a3, 32);
        const unsigned w0 = hi ? x2 : a0;
        const unsigned w1 = hi ? x3 : a1;
        const unsigned w2 = hi ? a2 : x0;
        const unsigned w3 = hi ? a3 : x1;
        union { u32x4 u; bf16x8 v; } cv;
        cv.u = (u32x4){w0, w1, w2, w3};
        const bf16x8 pa = cv.v;
        const int ttc = tt * 2 + c;
        accO[0] = MFMA32(pa, vf[ttc][0], accO[0]);
        accO[1] = MFMA32(pa, vf[ttc][1], accO[1]);
      }
    }
  }

  // ---- KV-split combine: half1 publishes, half0 merges + stores ----
  if (half == 1) {
    mlb[slot][0][lane] = m_run;
    mlb[slot][1][lane] = l_run;
#pragma unroll
    for (int dt = 0; dt < 2; ++dt)
#pragma unroll
      for (int c = 0; c < 4; ++c) {
        f32x4 ch = { accO[dt][c * 4 + 0], accO[dt][c * 4 + 1],
                     accO[dt][c * 4 + 2], accO[dt][c * 4 + 3] };
        *reinterpret_cast<f32x4*>(&olb[slot][lane][dt * 16 + c * 4]) = ch;
      }
  }
  __syncthreads();
  if (half == 0) {
    const float mB = mlb[slot][0][lane];
    const float lB = mlb[slot][1][lane];
    const float mN = fmaxf(m_run, mB);
    const float eA = exp2f(m_run - mN);
    const float eB = exp2f(mB - mN);
    const float lN = l_run * eA + lB * eB;
    const float inv = 1.0f / lN;         // per q = l31
    float eAr[16], eBr[16], ivr[16];
#pragma unroll
    for (int r = 0; r < 16; ++r) {
      const int qrow = (r & 3) + ((r >> 2) << 3) + hi * 4;
      eAr[r] = __shfl(eA, qrow);
      eBr[r] = __shfl(eB, qrow);
      ivr[r] = __shfl(inv, qrow);
    }
    const int b = bh >> 4, h = bh & 15;
#pragma unroll
    for (int dt = 0; dt < 2; ++dt) {
#pragma unroll
      for (int c = 0; c < 4; ++c) {
        const f32x4 ob = *reinterpret_cast<const f32x4*>(&olb[slot][lane][dt * 16 + c * 4]);
#pragma unroll
        for (int j = 0; j < 4; ++j) {
          const int r = c * 4 + j;
          const int qrow = (r & 3) + ((r >> 2) << 3) + hi * 4;
          const int qo = q0 + qrow;
          const float val = (accO[dt][r] * eAr[r] + ob[j] * eBr[r]) * ivr[r];
          Ob[((size_t)(b * S_LEN + qo)) * DMODEL + h * HDK + dt * 32 + l31] = (__bf16)val;
        }
      }
    }
  }
}

extern "C" void kernel_launch(void* const* d_in, const int* in_sizes, int n_in,
                              void* d_out, int out_size, void* d_ws, size_t ws_size,
                              hipStream_t stream) {
  const float* x = (const float*)d_in[0];
  const int* tpos = (const int*)d_in[1];
  const float* Wq = (const float*)d_in[2];
  const float* Wk = (const float*)d_in[3];
  const float* Wv = (const float*)d_in[4];
  const float* Wo = (const float*)d_in[5];
  float* out = (float*)d_out;

  __bf16* ws = (__bf16*)d_ws;
  __bf16* Xb = ws;                    // 4096x1024
  __bf16* Wqb = Xb + 4194304;         // 1024x1024
  __bf16* Wkb = Wqb + 1048576;
  __bf16* Wvb = Wkb + 1048576;
  __bf16* Wob = Wvb + 1048576;
  __bf16* Qr = Wob + 1048576;         // [2][16] QK-tiled planes
  __bf16* Kr = Qr + 4194304;
  __bf16* Vt = Kr + 4194304;          // [2][16] V-tiled planes
  __bf16* Ob = Vt + 4194304;          // 4096x1024
  float2* rtab = (float2*)(Ob + 4194304);  // [4096][32] cos/sin

  k_cvt<<<4096, 256, 0, stream>>>(x, Xb, 1048576);
  k_cvt<<<1024, 256, 0, stream>>>(Wq, Wqb, 262144);
  k_cvt<<<1024, 256, 0, stream>>>(Wk, Wkb, 262144);
  k_cvt<<<1024, 256, 0, stream>>>(Wv, Wvb, 262144);
  k_cvt<<<1024, 256, 0, stream>>>(Wo, Wob, 262144);
  k_rope<<<512, 256, 0, stream>>>(tpos, rtab);

  dim3 g1(32, 8, 3);
  k_qkv<<<g1, 256, 0, stream>>>(Xb, Wqb, Wkb, Wvb, rtab, Qr, Kr, Vt);

  k_attn<<<1024, 256, 0, stream>>>(Qr, Kr, Vt, Ob);

  dim3 g2(32, 8);
  k_oproj<<<g2, 256, 0, stream>>>(Ob, Wob, out);
}

// Round 11
// 114.569 us; speedup vs baseline: 2.0034x; 1.0507x over previous
//
#include <hip/hip_runtime.h>
#include <hip/hip_bf16.h>
#include <cstdint>
#include <cstddef>

#define S_LEN 2048
#define DMODEL 1024
#define NHEAD 16
#define HDK 64
#define LOG2E 1.44269504088896340736f

typedef __attribute__((ext_vector_type(8))) __bf16 bf16x8;
typedef __attribute__((ext_vector_type(4))) __bf16 bf16x4;
typedef __attribute__((ext_vector_type(4))) float f32x4;
typedef __attribute__((ext_vector_type(16))) float f32x16;
typedef __attribute__((ext_vector_type(4))) unsigned int u32x4;

#define MFMA16(a, b, c) __builtin_amdgcn_mfma_f32_16x16x32_bf16((a), (b), (c), 0, 0, 0)
// reversed operand order: D reg-dim = B-rows (2nd source arg), D lane-dim = A-rows
#define MFMA16R(a, b, c) __builtin_amdgcn_mfma_f32_16x16x32_bf16((b), (a), (c), 0, 0, 0)
#define MFMA32(a, b, c) __builtin_amdgcn_mfma_f32_32x32x16_bf16((a), (b), (c), 0, 0, 0)

// async global->LDS, 16B per lane; LDS dest = wave-uniform base + lane*16
#define GLL16(g, l)                                                        \
  __builtin_amdgcn_global_load_lds(                                        \
      (const __attribute__((address_space(1))) unsigned int*)(g),          \
      (__attribute__((address_space(3))) unsigned int*)(l), 16, 0, 0)

// Fragment-tiled layouts (per (b,h) plane of S_LEN x 64):
__device__ __forceinline__ size_t qk_off(int s, int d) {
  return ((((size_t)(s >> 5) * 4 + (d >> 4)) * 2 + ((d >> 3) & 1)) * 32 + (s & 31)) * 8 + (d & 7);
}
__device__ __forceinline__ size_t v_off(int s, int d) {
  return ((size_t)(s >> 4) * 64 + d) * 16 + (s & 15);
}

// pack two f32 -> one dword of 2 bf16 (lo = first)
__device__ __forceinline__ unsigned pk2(float a, float b) {
  union { __bf16 h[2]; unsigned u; } cv;
  cv.h[0] = (__bf16)a;
  cv.h[1] = (__bf16)b;
  return cv.u;
}

// ---------------- f32 -> bf16 convert ----------------
__global__ __launch_bounds__(256) void k_cvt(const float* __restrict__ src,
                                             __bf16* __restrict__ dst, int n4) {
  const int i = blockIdx.x * 256 + threadIdx.x;
  if (i >= n4) return;
  const float4 v = reinterpret_cast<const float4*>(src)[i];
  bf16x4 o = { (__bf16)v.x, (__bf16)v.y, (__bf16)v.z, (__bf16)v.w };
  reinterpret_cast<bf16x4*>(dst)[i] = o;
}

// all four 1024x1024 weights in one launch (dst planes contiguous in ws)
__global__ __launch_bounds__(256) void k_cvtw(
    const float* __restrict__ w0, const float* __restrict__ w1,
    const float* __restrict__ w2, const float* __restrict__ w3,
    __bf16* __restrict__ dst) {
  const int z = blockIdx.y;
  const float* src = (z == 0) ? w0 : (z == 1) ? w1 : (z == 2) ? w2 : w3;
  const int i = blockIdx.x * 256 + threadIdx.x;   // 262144 float4 per plane
  const float4 v = reinterpret_cast<const float4*>(src)[i];
  bf16x4 o = { (__bf16)v.x, (__bf16)v.y, (__bf16)v.z, (__bf16)v.w };
  reinterpret_cast<bf16x4*>(dst + (size_t)z * 1048576)[i] = o;
}

// ---------------- RoPE table, TRANSPOSED: tab[i][m] = (cos,sin)(pos[m]*theta^(-i/32)) ----
__global__ __launch_bounds__(256) void k_rope(const int* __restrict__ tpos,
                                              float2* __restrict__ tab) {
  const int idx = blockIdx.x * 256 + threadIdx.x;   // [0, 32*4096)
  const int i = idx >> 12, m = idx & 4095;
  const float invf = exp2f(-(float)i * (13.287712379549449f / 32.0f));
  const float ang = (float)tpos[m] * invf;
  tab[idx] = make_float2(cosf(ang), sinf(ang));
}

// ================= 128x128 m97-structure GEMM core =================
// MFMA_OP = MFMA16  : D lane-dim = B-rows (e), reg-dim = A-rows (m)   [oproj]
// MFMA_OP = MFMA16R : D lane-dim = A-rows (m), reg-dim = B-rows (e)   [qkv]
#define GEMM128_CORE(Abase, Bbase, MFMA_OP)                                    \
  __shared__ __align__(16) __bf16 As[128 * 64];                                \
  __shared__ __align__(16) __bf16 Bs[128 * 64];                                \
  const int t = threadIdx.x;                                                   \
  const int lane = t & 63;                                                     \
  const int w = t >> 6;                                                        \
  const int wm = (w >> 1) * 64;                                                \
  const int wn = (w & 1) * 64;                                                 \
  const int l15 = lane & 15, lhi = lane >> 4;                                  \
  const int lr = lane >> 3;               /* staging row-in-group 0..7 */      \
  const int ls = (lane & 7) ^ lr;         /* swizzled source slot */           \
  const int srow = w * 32 + lr;           /* staging row (+c*8) */             \
  const __bf16* gA = (Abase) + (size_t)(m0 + srow) * DMODEL + ls * 8;          \
  const __bf16* gB = (Bbase) + (size_t)(n0 + srow) * DMODEL + ls * 8;          \
  const f32x4 z4 = {0.f, 0.f, 0.f, 0.f};                                       \
  f32x4 acc[4][4];                                                             \
  _Pragma("unroll") for (int i = 0; i < 4; ++i)                                \
      _Pragma("unroll") for (int j = 0; j < 4; ++j) acc[i][j] = z4;            \
  for (int k0 = 0; k0 < DMODEL; k0 += 64) {                                    \
    _Pragma("unroll") for (int c = 0; c < 4; ++c) {                            \
      GLL16(gA + k0 + (size_t)c * 8 * DMODEL, &As[w * 2048 + c * 512]);        \
      GLL16(gB + k0 + (size_t)c * 8 * DMODEL, &Bs[w * 2048 + c * 512]);        \
    }                                                                          \
    __syncthreads();                                                           \
    _Pragma("unroll") for (int kk = 0; kk < 2; ++kk) {                         \
      const int sw = ((kk * 4 + lhi) ^ (l15 & 7)) * 8;                         \
      bf16x8 af[4], bf[4];                                                     \
      _Pragma("unroll") for (int i = 0; i < 4; ++i) {                          \
        af[i] = *reinterpret_cast<const bf16x8*>(                              \
            &As[(wm + i * 16 + l15) * 64 + sw]);                               \
        bf[i] = *reinterpret_cast<const bf16x8*>(                              \
            &Bs[(wn + i * 16 + l15) * 64 + sw]);                               \
      }                                                                        \
      _Pragma("unroll") for (int i = 0; i < 4; ++i)                            \
          _Pragma("unroll") for (int j = 0; j < 4; ++j)                        \
              acc[i][j] = MFMA_OP(af[i], bf[j], acc[i][j]);                    \
    }                                                                          \
    __syncthreads();                                                           \
  }

// ---------------- fused QKV projection + RoPE (128x128, swapped operands) ----------
// Lane dim = m (sequence), reg dim = e (feature): RoPE pairs are adjacent regs of
// the SAME lane -> no shuffles; rtabT loads coalesced; Q/K pair stored as ushort2.
// z=0: Q (rope, pre-scaled 0.125*log2e)  z=1: K (rope)  z=2: V (V-tiled)
__global__ __launch_bounds__(256) void k_qkv(
    const __bf16* __restrict__ Xb,
    const __bf16* __restrict__ Wqb, const __bf16* __restrict__ Wkb,
    const __bf16* __restrict__ Wvb, const float2* __restrict__ rtab,
    __bf16* __restrict__ Qr, __bf16* __restrict__ Kr, __bf16* __restrict__ Vt) {
  const int z = blockIdx.z;
  const __bf16* W = (z == 0) ? Wqb : (z == 1) ? Wkb : Wvb;
  const int m0 = blockIdx.x * 128;
  const int n0 = blockIdx.y * 128;

  GEMM128_CORE(Xb, W, MFMA16R)

  if (z < 2) {
    __bf16* Out = (z == 0) ? Qr : Kr;
    const float oscale = (z == 0) ? 0.125f * LOG2E : 1.0f;
#pragma unroll
    for (int i = 0; i < 4; ++i) {
      const int m = m0 + wm + i * 16 + l15;
      const int bb = m >> 11, ss = m & (S_LEN - 1);
#pragma unroll
      for (int j = 0; j < 4; ++j) {
        const int ebase = n0 + wn + j * 16 + lhi * 4;
        const int h = ebase >> 6;
        __bf16* plane = Out + (size_t)(bb * NHEAD + h) * (S_LEN * HDK);
#pragma unroll
        for (int rp = 0; rp < 2; ++rp) {
          const int dkI = (ebase + rp * 2) & 63;     // even
          const float2 cssn = rtab[(size_t)(dkI >> 1) * 4096 + m];
          const float x1 = acc[i][j][rp * 2];
          const float x2 = acc[i][j][rp * 2 + 1];
          const float oe = (x1 * cssn.x - x2 * cssn.y) * oscale;
          const float oo = (x1 * cssn.y + x2 * cssn.x) * oscale;
          union { __bf16 h2[2]; ushort2 u2; } pk;
          pk.h2[0] = (__bf16)oe;
          pk.h2[1] = (__bf16)oo;
          *reinterpret_cast<ushort2*>(&plane[qk_off(ss, dkI)]) = pk.u2;
        }
      }
    }
  } else {
#pragma unroll
    for (int i = 0; i < 4; ++i) {
      const int m = m0 + wm + i * 16 + l15;
      const int bb = m >> 11, ss = m & (S_LEN - 1);
#pragma unroll
      for (int j = 0; j < 4; ++j) {
        const int ebase = n0 + wn + j * 16 + lhi * 4;
        const int h = ebase >> 6;
        __bf16* plane = Vt + (size_t)(bb * NHEAD + h) * (S_LEN * HDK);
#pragma unroll
        for (int r = 0; r < 4; ++r) {
          const int d = (ebase + r) & 63;
          plane[v_off(ss, d)] = (__bf16)acc[i][j][r];   // 16-lane 32B runs
        }
      }
    }
  }
}

// ---------------- output projection (128x128, f32 out, normal operand order) ------
__global__ __launch_bounds__(256) void k_oproj(
    const __bf16* __restrict__ Ob, const __bf16* __restrict__ Wob,
    float* __restrict__ out) {
  const int m0 = blockIdx.x * 128;
  const int n0 = blockIdx.y * 128;

  GEMM128_CORE(Ob, Wob, MFMA16)

#pragma unroll
  for (int mi = 0; mi < 4; ++mi) {
#pragma unroll
    for (int ni = 0; ni < 4; ++ni) {
      const int e = n0 + wn + ni * 16 + l15;
#pragma unroll
      for (int r = 0; r < 4; ++r) {
        const int m = m0 + wm + mi * 16 + lhi * 4 + r;
        out[(size_t)m * DMODEL + e] = acc[mi][ni][r];
      }
    }
  }
}

// ---------------- causal flash attention (QBLK=32, 32x32 MFMA, KV-split x2) ----------
// Round-9 verified structure (shfl_xor reduces + shfl/select PV frag build) with the
// padded combine buffer. No inline-asm lane ops (R10's aliased-operand asm reverted).
__global__ __launch_bounds__(256, 2) void k_attn(
    const __bf16* __restrict__ Qr, const __bf16* __restrict__ Kr,
    const __bf16* __restrict__ Vt, __bf16* __restrict__ Ob) {
  const int t = threadIdx.x, lane = t & 63, w = t >> 6;
  const int blk = blockIdx.x;            // 1024 blocks
  const int qp = blk >> 5;               // 0..31 qtile-pair, heavy-first
  const int bh = blk & 31;
  const int slot = w >> 1;               // which qtile in block (0,1)
  const int half = w & 1;                // k-range half
  const int qtile = (31 - qp) * 2 + slot;  // 0..63
  const int q0 = qtile * 32;
  const int l31 = lane & 31, hi = lane >> 5;

  const __bf16* Q = Qr + (size_t)bh * (S_LEN * HDK);
  const __bf16* K = Kr + (size_t)bh * (S_LEN * HDK);
  const __bf16* V = Vt + (size_t)bh * (S_LEN * HDK);

  __shared__ float mlb[2][2][64];            // half1 stats (m, l)
  __shared__ float olb[2][64][33];           // half1 accO, padded: bank=(lane+c)%32

  // Q fragments: row q=l31, d = dc*16 + hi*8 + j  (tiled: dense, lane-stride 16B)
  bf16x8 qf[4];
#pragma unroll
  for (int dc = 0; dc < 4; ++dc)
    qf[dc] = *reinterpret_cast<const bf16x8*>(
        &Q[((((size_t)(q0 >> 5) * 4 + dc) * 2 + hi) * 32 + l31) * 8]);

  f32x16 accO[2] = {};
  float m_run = -3e30f, l_run = 0.0f;
  const int q = q0 + l31;
  const int kmax = q0 + 32;

  // preload K fragments for first k0 of this half
  const int kstart = 64 * half;
  bf16x8 kf[2][4];
#pragma unroll
  for (int tt = 0; tt < 2; ++tt)
#pragma unroll
    for (int dc = 0; dc < 4; ++dc)
      kf[tt][dc] = *reinterpret_cast<const bf16x8*>(
          &K[((((size_t)((kstart >> 5) + tt) * 4 + dc) * 2 + hi) * 32 + l31) * 8]);

  for (int k0 = kstart; k0 < kmax; k0 += 128) {
    // ---- prefetch V fragments for THIS iteration ----
    bf16x8 vf[4][2];
#pragma unroll
    for (int ttc = 0; ttc < 4; ++ttc) {
      const int kc = k0 + ttc * 16;
#pragma unroll
      for (int d0h = 0; d0h < 2; ++d0h)
        vf[ttc][d0h] = *reinterpret_cast<const bf16x8*>(
            &V[((size_t)(kc >> 4) * 64 + d0h * 32 + l31) * 16 + hi * 8]);
    }

    // ---- QK^T (swapped): two 32k x 32q tiles ----
    f32x16 sT0 = {}, sT1 = {};
#pragma unroll
    for (int dc = 0; dc < 4; ++dc) {
      sT0 = MFMA32(kf[0][dc], qf[dc], sT0);
      sT1 = MFMA32(kf[1][dc], qf[dc], sT1);
    }

    // ---- reload K fragments for NEXT iteration of this half ----
    if (k0 + 128 < kmax) {
      const int kn = (k0 + 128) >> 5;
#pragma unroll
      for (int tt = 0; tt < 2; ++tt)
#pragma unroll
        for (int dc = 0; dc < 4; ++dc)
          kf[tt][dc] = *reinterpret_cast<const bf16x8*>(
              &K[((((size_t)(kn + tt) * 4 + dc) * 2 + hi) * 32 + l31) * 8]);
    }

    // ---- causal mask (uniform branch; only diagonal tiles pay) ----
    const bool maskIt = (k0 + 63 > q0);
    if (maskIt) {
#pragma unroll
      for (int r = 0; r < 16; ++r) {
        const int kb = (r & 3) + ((r >> 2) << 3) + hi * 4;
        if (k0 + kb > q) sT0[r] = -3e30f;
        if (k0 + 32 + kb > q) sT1[r] = -3e30f;
      }
    }

    // ---- tree row-max + cross-half shfl reduce ----
    float pm[8];
#pragma unroll
    for (int j = 0; j < 8; ++j)
      pm[j] = fmaxf(fmaxf(sT0[2 * j], sT0[2 * j + 1]),
                    fmaxf(sT1[2 * j], sT1[2 * j + 1]));
    pm[0] = fmaxf(pm[0], pm[4]); pm[1] = fmaxf(pm[1], pm[5]);
    pm[2] = fmaxf(pm[2], pm[6]); pm[3] = fmaxf(pm[3], pm[7]);
    float mx = fmaxf(fmaxf(pm[0], pm[1]), fmaxf(pm[2], pm[3]));
    mx = fmaxf(mx, __shfl_xor(mx, 32));

    // ---- defer-max (log2 units) ----
    float sc = 1.0f;
    if (!__all(mx <= m_run + 8.0f)) {
      const float mn = fmaxf(m_run, mx);
      sc = exp2f(m_run - mn);
      m_run = mn;
      float scA[16];
#pragma unroll
      for (int r = 0; r < 16; ++r)
        scA[r] = __shfl(sc, (r & 3) + ((r >> 2) << 3) + hi * 4);
#pragma unroll
      for (int dt = 0; dt < 2; ++dt)
#pragma unroll
        for (int r = 0; r < 16; ++r) accO[dt][r] *= scA[r];
    }

    // ---- exp2 + tree running sum + pack to bf16 dwords ----
    float rsp[4] = {0.f, 0.f, 0.f, 0.f};
    unsigned pd[16];
#pragma unroll
    for (int j = 0; j < 8; ++j) {
      const float p0 = exp2f(sT0[2 * j] - m_run);
      const float p1 = exp2f(sT0[2 * j + 1] - m_run);
      const float p2 = exp2f(sT1[2 * j] - m_run);
      const float p3 = exp2f(sT1[2 * j + 1] - m_run);
      rsp[j & 3] += (p0 + p1) + (p2 + p3);
      pd[j] = pk2(p0, p1);
      pd[8 + j] = pk2(p2, p3);
    }
    float rs = (rsp[0] + rsp[1]) + (rsp[2] + rsp[3]);
    rs += __shfl_xor(rs, 32);
    l_run = l_run * sc + rs;

    // ---- PV: build A-frags via cross-half shfl + select (verified R5 form) ----
#pragma unroll
    for (int tt = 0; tt < 2; ++tt) {
#pragma unroll
      for (int c = 0; c < 2; ++c) {
        const int base = tt * 8 + c * 4;
        const unsigned a0 = pd[base + 0], a1 = pd[base + 1];
        const unsigned a2 = pd[base + 2], a3 = pd[base + 3];
        const unsigned x0 = __shfl_xor(a0, 32), x1 = __shfl_xor(a1, 32);
        const unsigned x2 = __shfl_xor(a2, 32), x3 = __shfl_xor(a3, 32);
        const unsigned w0 = hi ? x2 : a0;
        const unsigned w1 = hi ? x3 : a1;
        const unsigned w2 = hi ? a2 : x0;
        const unsigned w3 = hi ? a3 : x1;
        union { u32x4 u; bf16x8 v; } cv;
        cv.u = (u32x4){w0, w1, w2, w3};
        const bf16x8 pa = cv.v;
        const int ttc = tt * 2 + c;
        accO[0] = MFMA32(pa, vf[ttc][0], accO[0]);
        accO[1] = MFMA32(pa, vf[ttc][1], accO[1]);
      }
    }
  }

  // ---- KV-split combine: half1 publishes, half0 merges + stores ----
  if (half == 1) {
    mlb[slot][0][lane] = m_run;
    mlb[slot][1][lane] = l_run;
#pragma unroll
    for (int dt = 0; dt < 2; ++dt)
#pragma unroll
      for (int r = 0; r < 16; ++r)
        olb[slot][lane][dt * 16 + r] = accO[dt][r];
  }
  __syncthreads();
  if (half == 0) {
    const float mB = mlb[slot][0][lane];
    const float lB = mlb[slot][1][lane];
    const float mN = fmaxf(m_run, mB);
    const float eA = exp2f(m_run - mN);
    const float eB = exp2f(mB - mN);
    const float lN = l_run * eA + lB * eB;
    const float inv = 1.0f / lN;         // per q = l31
    float eAr[16], eBr[16], ivr[16];
#pragma unroll
    for (int r = 0; r < 16; ++r) {
      const int qrow = (r & 3) + ((r >> 2) << 3) + hi * 4;
      eAr[r] = __shfl(eA, qrow);
      eBr[r] = __shfl(eB, qrow);
      ivr[r] = __shfl(inv, qrow);
    }
    const int b = bh >> 4, h = bh & 15;
#pragma unroll
    for (int dt = 0; dt < 2; ++dt) {
#pragma unroll
      for (int r = 0; r < 16; ++r) {
        const int qrow = (r & 3) + ((r >> 2) << 3) + hi * 4;
        const int qo = q0 + qrow;
        const float ob = olb[slot][lane][dt * 16 + r];
        const float val = (accO[dt][r] * eAr[r] + ob * eBr[r]) * ivr[r];
        Ob[((size_t)(b * S_LEN + qo)) * DMODEL + h * HDK + dt * 32 + l31] = (__bf16)val;
      }
    }
  }
}

extern "C" void kernel_launch(void* const* d_in, const int* in_sizes, int n_in,
                              void* d_out, int out_size, void* d_ws, size_t ws_size,
                              hipStream_t stream) {
  const float* x = (const float*)d_in[0];
  const int* tpos = (const int*)d_in[1];
  const float* Wq = (const float*)d_in[2];
  const float* Wk = (const float*)d_in[3];
  const float* Wv = (const float*)d_in[4];
  const float* Wo = (const float*)d_in[5];
  float* out = (float*)d_out;

  __bf16* ws = (__bf16*)d_ws;
  __bf16* Xb = ws;                    // 4096x1024
  __bf16* Wqb = Xb + 4194304;         // 4 x 1024x1024, contiguous
  __bf16* Wkb = Wqb + 1048576;
  __bf16* Wvb = Wkb + 1048576;
  __bf16* Wob = Wvb + 1048576;
  __bf16* Qr = Wob + 1048576;         // [2][16] QK-tiled planes
  __bf16* Kr = Qr + 4194304;
  __bf16* Vt = Kr + 4194304;          // [2][16] V-tiled planes
  __bf16* Ob = Vt + 4194304;          // 4096x1024
  float2* rtab = (float2*)(Ob + 4194304);  // [32][4096] cos/sin (transposed)

  k_cvt<<<4096, 256, 0, stream>>>(x, Xb, 1048576);
  k_cvtw<<<dim3(1024, 4), 256, 0, stream>>>(Wq, Wk, Wv, Wo, Wqb);
  k_rope<<<512, 256, 0, stream>>>(tpos, rtab);

  dim3 g1(32, 8, 3);
  k_qkv<<<g1, 256, 0, stream>>>(Xb, Wqb, Wkb, Wvb, rtab, Qr, Kr, Vt);

  k_attn<<<1024, 256, 0, stream>>>(Qr, Kr, Vt, Ob);

  dim3 g2(32, 8);
  k_oproj<<<g2, 256, 0, stream>>>(Ob, Wob, out);
}